// Round 1
// baseline (526.082 us; speedup 1.0000x reference)
//
#include <hip/hip_runtime.h>

// Sizes: B=64, T=64, D=256, N=128, K=128, BASIS=8, F=1024
// ws layout (floats):
//  Wmat   @ 0        (2097152)   dead after k_local
//  Aws    @ 2097152  (16384)     dead after k_globalmix
//  M      @ 2113536  (1048576)   dead after k_local
//  XL     @ 3162112  (1048576)   dead after k_globalmix
//  GX     @ 4210688  (1048576)   dead after k_mid
//  MX     @ 5259264  (1048576)
//  MY     @ 6307840  (1048576)
//  PF     @ 7356416  (1048576)   dead after k_gateup
//  HID    @ 0        (4194304)   overlays Wmat/Aws/M/XL (all dead)
//  P0     @ 4210688  (1048576)   overlays GX (dead)
//  P1     @ 8404992  (1048576)
// total 9453568 floats = 37.8 MB

__device__ __forceinline__ float wave_sum(float x) {
#pragma unroll
  for (int o = 32; o >= 1; o >>= 1) x += __shfl_xor(x, o, 64);
  return x;
}

// ---------------- Kernel A: sinkhorn via dual potentials ----------------
extern "C" __global__ void __launch_bounds__(256) k_sink(
    const float* __restrict__ Alog, const float* __restrict__ W1,
    const float* __restrict__ WV, float* __restrict__ Wout,
    float* __restrict__ Aout) {
  extern __shared__ float sm[];
  float* laT = sm;             // [128][132] transposed la0
  float* u_s = sm + 128 * 132; // [128]
  float* v_s = u_s + 128;      // [128]
  const int t = threadIdx.x;
  const int n = blockIdx.x;
  const int r = t >> 1, j = t & 1, c0 = j * 64;
  float la[64];
  if (n < 128) {
    float w1v[8];
#pragma unroll
    for (int s = 0; s < 8; ++s) w1v[s] = W1[n * 8 + s];
#pragma unroll
    for (int i4 = 0; i4 < 16; ++i4) {
      float a0 = 0.f, a1 = 0.f, a2 = 0.f, a3 = 0.f;
#pragma unroll
      for (int s = 0; s < 8; ++s) {
        const float4 wv = *(const float4*)&WV[s * 16384 + r * 128 + c0 + i4 * 4];
        a0 += w1v[s] * wv.x; a1 += w1v[s] * wv.y;
        a2 += w1v[s] * wv.z; a3 += w1v[s] * wv.w;
      }
      la[i4 * 4 + 0] = 5.f * a0; la[i4 * 4 + 1] = 5.f * a1;
      la[i4 * 4 + 2] = 5.f * a2; la[i4 * 4 + 3] = 5.f * a3;
    }
  } else {
#pragma unroll
    for (int i4 = 0; i4 < 16; ++i4) {
      const float4 av = *(const float4*)&Alog[r * 128 + c0 + i4 * 4];
      la[i4 * 4 + 0] = 5.f * av.x; la[i4 * 4 + 1] = 5.f * av.y;
      la[i4 * 4 + 2] = 5.f * av.z; la[i4 * 4 + 3] = 5.f * av.w;
    }
  }
#pragma unroll
  for (int i = 0; i < 64; ++i) laT[(c0 + i) * 132 + r] = la[i];
  if (t < 128) { u_s[t] = 0.f; v_s[t] = 0.f; }
  __syncthreads();
  for (int it = 0; it < 20; ++it) {
    // u[r] = log sum_c exp(la0[r,c] - v[c])
    float s = 0.f;
#pragma unroll
    for (int i4 = 0; i4 < 16; ++i4) {
      const float4 v4 = *(const float4*)&v_s[c0 + i4 * 4];
      s += __expf(la[i4 * 4 + 0] - v4.x) + __expf(la[i4 * 4 + 1] - v4.y) +
           __expf(la[i4 * 4 + 2] - v4.z) + __expf(la[i4 * 4 + 3] - v4.w);
    }
    s += __shfl_xor(s, 1, 64);
    if (j == 0) u_s[r] = __logf(s);
    __syncthreads();
    // v[c] = log sum_r exp(la0[r,c] - u[r]) ; this thread handles column r
    float sv = 0.f;
#pragma unroll
    for (int i4 = 0; i4 < 16; ++i4) {
      const float4 u4 = *(const float4*)&u_s[c0 + i4 * 4];
      const float4 l4 = *(const float4*)&laT[r * 132 + c0 + i4 * 4];
      sv += __expf(l4.x - u4.x) + __expf(l4.y - u4.y) +
            __expf(l4.z - u4.z) + __expf(l4.w - u4.w);
    }
    sv += __shfl_xor(sv, 1, 64);
    if (j == 0) v_s[r] = __logf(sv);
    __syncthreads();
  }
  const float ur = u_s[r];
  float* outp = (n < 128) ? (Wout + n * 16384) : Aout;
#pragma unroll
  for (int i4 = 0; i4 < 16; ++i4) {
    const float4 v4 = *(const float4*)&v_s[c0 + i4 * 4];
    float4 p;
    p.x = __expf(la[i4 * 4 + 0] - ur - v4.x);
    p.y = __expf(la[i4 * 4 + 1] - ur - v4.y);
    p.z = __expf(la[i4 * 4 + 2] - ur - v4.z);
    p.w = __expf(la[i4 * 4 + 3] - ur - v4.w);
    *(float4*)&outp[r * 128 + c0 + i4 * 4] = p;
  }
}

// ---------------- Kernel B: mixing_input = src_x + LN(src_y) ----------------
extern "C" __global__ void __launch_bounds__(256) k_premix(
    const float* __restrict__ sx, const float* __restrict__ sy,
    const float* __restrict__ g, const float* __restrict__ b,
    float* __restrict__ M) {
  const int lane = threadIdx.x & 63;
  const int row = blockIdx.x * 4 + (threadIdx.x >> 6);
  const int idx = row * 256 + lane * 4;
  const float4 y4 = *(const float4*)&sy[idx];
  const float4 x4 = *(const float4*)&sx[idx];
  float s1 = y4.x + y4.y + y4.z + y4.w;
  float s2 = y4.x * y4.x + y4.y * y4.y + y4.z * y4.z + y4.w * y4.w;
  s1 = wave_sum(s1); s2 = wave_sum(s2);
  const float mu = s1 * (1.f / 256.f);
  const float rs = rsqrtf(s2 * (1.f / 256.f) - mu * mu + 1e-5f);
  const float4 g4 = *(const float4*)&g[lane * 4];
  const float4 b4 = *(const float4*)&b[lane * 4];
  float4 m4;
  m4.x = x4.x + (y4.x - mu) * rs * g4.x + b4.x;
  m4.y = x4.y + (y4.y - mu) * rs * g4.y + b4.y;
  m4.z = x4.z + (y4.z - mu) * rs * g4.z + b4.z;
  m4.w = x4.w + (y4.w - mu) * rs * g4.w + b4.w;
  *(float4*)&M[idx] = m4;
}

// ---------------- Kernel C: XL0[b,n,:] = xr[b,n,:] @ W[n] ----------------
extern "C" __global__ void __launch_bounds__(256) k_local(
    const float* __restrict__ M, const float* __restrict__ Wmat,
    float* __restrict__ XL) {
  extern __shared__ float sm[];
  float* Wl = sm;                        // [128][128]
  float4* xr4 = (float4*)(sm + 16384);   // [32 k4][64 b]
  const int t = threadIdx.x;
  const int n = blockIdx.x;
  const int hi = n & 1, t2 = n >> 1;
#pragma unroll
  for (int jj = 0; jj < 16; ++jj)
    *(float4*)&Wl[jj * 1024 + t * 4] =
        *(const float4*)&Wmat[n * 16384 + jj * 1024 + t * 4];
  {
    const int b = t & 63, gq = t >> 6;
#pragma unroll
    for (int i = 0; i < 8; ++i) {
      const int q = gq * 8 + i;
      // xr[b][n][4q+c] = M[b][hi*32+q][4*t2+c]
      xr4[q * 64 + b] = *(const float4*)&M[b * 16384 + (hi * 32 + q) * 256 + t2 * 4];
    }
  }
  __syncthreads();
  const int kblk = t & 31, bblk = t >> 5;
  const int ko0 = kblk * 4, b0 = bblk * 8;
  float acc[8][4];
#pragma unroll
  for (int i = 0; i < 8; ++i)
    acc[i][0] = acc[i][1] = acc[i][2] = acc[i][3] = 0.f;
  for (int q = 0; q < 32; ++q) {
    const float4 w0 = *(const float4*)&Wl[(4 * q + 0) * 128 + ko0];
    const float4 w1 = *(const float4*)&Wl[(4 * q + 1) * 128 + ko0];
    const float4 w2 = *(const float4*)&Wl[(4 * q + 2) * 128 + ko0];
    const float4 w3 = *(const float4*)&Wl[(4 * q + 3) * 128 + ko0];
#pragma unroll
    for (int i = 0; i < 8; ++i) {
      const float4 xv = xr4[q * 64 + b0 + i];
      acc[i][0] += xv.x * w0.x + xv.y * w1.x + xv.z * w2.x + xv.w * w3.x;
      acc[i][1] += xv.x * w0.y + xv.y * w1.y + xv.z * w2.y + xv.w * w3.y;
      acc[i][2] += xv.x * w0.z + xv.y * w1.z + xv.z * w2.z + xv.w * w3.z;
      acc[i][3] += xv.x * w0.w + xv.y * w1.w + xv.z * w2.w + xv.w * w3.w;
    }
  }
#pragma unroll
  for (int i = 0; i < 8; ++i) {
    float4 o;
    o.x = acc[i][0]; o.y = acc[i][1]; o.z = acc[i][2]; o.w = acc[i][3];
    *(float4*)&XL[(b0 + i) * 16384 + n * 128 + ko0] = o;
  }
}

// --------- Kernel D: column-LN over n (folded) + @A + transpose -> GX ---------
extern "C" __global__ void __launch_bounds__(256) k_globalmix(
    const float* __restrict__ XLg, const float* __restrict__ Ain,
    const float* __restrict__ g2, const float* __restrict__ b2,
    float* __restrict__ GX) {
  extern __shared__ float sm[];
  float* XL = sm;            // [m][k]
  float* Ag = sm + 16384;    // [m][n]
  float* mu_s = Ag + 16384;
  float* rs_s = mu_s + 128;
  float* cg_s = rs_s + 128;
  float* cb_s = cg_s + 128;
  float* gg = cb_s + 128;
  float* bb = gg + 128;
  const int t = threadIdx.x;
  const int b = blockIdx.x;
#pragma unroll
  for (int jj = 0; jj < 16; ++jj) {
    *(float4*)&XL[jj * 1024 + t * 4] =
        *(const float4*)&XLg[b * 16384 + jj * 1024 + t * 4];
    *(float4*)&Ag[jj * 1024 + t * 4] = *(const float4*)&Ain[jj * 1024 + t * 4];
  }
  if (t < 128) { gg[t] = g2[t]; bb[t] = b2[t]; }
  __syncthreads();
  {
    const int k = t >> 1, h = t & 1;
    float s1 = 0.f, s2 = 0.f, sg = 0.f, sb = 0.f;
    for (int m = h * 64; m < h * 64 + 64; ++m) {
      const float x = XL[m * 128 + k];
      s1 += x; s2 += x * x;
      const float a = Ag[m * 128 + k];
      sg += gg[m] * a; sb += bb[m] * a;
    }
    s1 += __shfl_xor(s1, 1, 64); s2 += __shfl_xor(s2, 1, 64);
    sg += __shfl_xor(sg, 1, 64); sb += __shfl_xor(sb, 1, 64);
    if (h == 0) {
      const float mu = s1 * (1.f / 128.f);
      mu_s[k] = mu;
      rs_s[k] = rsqrtf(s2 * (1.f / 128.f) - mu * mu + 1e-5f);
      cg_s[k] = sg; cb_s[k] = sb;
    }
  }
  __syncthreads();
  {  // Ag[m][n] = g[m]*A[m][n] in place
    const int m = t >> 1, h = t & 1;
    const float gm = gg[m];
#pragma unroll
    for (int i4 = 0; i4 < 16; ++i4) {
      float4 a4 = *(float4*)&Ag[m * 128 + h * 64 + i4 * 4];
      a4.x *= gm; a4.y *= gm; a4.z *= gm; a4.w *= gm;
      *(float4*)&Ag[m * 128 + h * 64 + i4 * 4] = a4;
    }
  }
  __syncthreads();
  const int nblk = t & 15, kblk = t >> 4;
  const int n0 = nblk * 8, k0 = kblk * 8;
  float acc[8][8];
#pragma unroll
  for (int nn = 0; nn < 8; ++nn)
#pragma unroll
    for (int kk = 0; kk < 8; ++kk) acc[nn][kk] = 0.f;
  for (int m = 0; m < 128; ++m) {
    const float4 a0 = *(const float4*)&Ag[m * 128 + n0];
    const float4 a1 = *(const float4*)&Ag[m * 128 + n0 + 4];
    const float4 x0 = *(const float4*)&XL[m * 128 + k0];
    const float4 x1 = *(const float4*)&XL[m * 128 + k0 + 4];
    const float an[8] = {a0.x, a0.y, a0.z, a0.w, a1.x, a1.y, a1.z, a1.w};
    const float xk[8] = {x0.x, x0.y, x0.z, x0.w, x1.x, x1.y, x1.z, x1.w};
#pragma unroll
    for (int nn = 0; nn < 8; ++nn)
#pragma unroll
      for (int kk = 0; kk < 8; ++kk) acc[nn][kk] += an[nn] * xk[kk];
  }
#pragma unroll
  for (int nn = 0; nn < 8; ++nn) {
    const int nI = n0 + nn;
    const float cgn = cg_s[nI], cbn = cb_s[nI];
    float o[8];
#pragma unroll
    for (int kk = 0; kk < 8; ++kk)
      o[kk] = rs_s[k0 + kk] * (acc[nn][kk] - mu_s[k0 + kk] * cgn) + cbn;
    float4 o0, o1;
    o0.x = o[0]; o0.y = o[1]; o0.z = o[2]; o0.w = o[3];
    o1.x = o[4]; o1.y = o[5]; o1.z = o[6]; o1.w = o[7];
    *(float4*)&GX[b * 16384 + nI * 128 + k0] = o0;
    *(float4*)&GX[b * 16384 + nI * 128 + k0 + 4] = o1;
  }
}

// ---------------- Kernel E: mid_x / mid_y / pffn ----------------
extern "C" __global__ void __launch_bounds__(256) k_mid(
    const float* __restrict__ sx, const float* __restrict__ sy,
    const float* __restrict__ GX, const float* __restrict__ g_px,
    const float* __restrict__ b_px, const float* __restrict__ g_pf,
    const float* __restrict__ b_pf, float* __restrict__ MX,
    float* __restrict__ MY, float* __restrict__ PF) {
  const int lane = threadIdx.x & 63;
  const int row = blockIdx.x * 4 + (threadIdx.x >> 6);
  const int idx = row * 256 + lane * 4;
  const float4 x4 = *(const float4*)&sx[idx];
  const float4 y4 = *(const float4*)&sy[idx];
  const float4 h4 = *(const float4*)&GX[idx];
  float4 t4;
  t4.x = x4.x + h4.x; t4.y = x4.y + h4.y; t4.z = x4.z + h4.z; t4.w = x4.w + h4.w;
  {
    float s1 = t4.x + t4.y + t4.z + t4.w;
    float s2 = t4.x * t4.x + t4.y * t4.y + t4.z * t4.z + t4.w * t4.w;
    s1 = wave_sum(s1); s2 = wave_sum(s2);
    const float mu = s1 * (1.f / 256.f);
    const float rs = rsqrtf(s2 * (1.f / 256.f) - mu * mu + 1e-5f);
    const float4 g4 = *(const float4*)&g_px[lane * 4];
    const float4 b4 = *(const float4*)&b_px[lane * 4];
    t4.x = (t4.x - mu) * rs * g4.x + b4.x;
    t4.y = (t4.y - mu) * rs * g4.y + b4.y;
    t4.z = (t4.z - mu) * rs * g4.z + b4.z;
    t4.w = (t4.w - mu) * rs * g4.w + b4.w;
  }
  *(float4*)&MX[idx] = t4;  // mid_x
  float4 my4;
  my4.x = y4.x + h4.x; my4.y = y4.y + h4.y;
  my4.z = y4.z + h4.z; my4.w = y4.w + h4.w;
  *(float4*)&MY[idx] = my4;
  {
    float s1 = my4.x + my4.y + my4.z + my4.w;
    float s2 = my4.x * my4.x + my4.y * my4.y + my4.z * my4.z + my4.w * my4.w;
    s1 = wave_sum(s1); s2 = wave_sum(s2);
    const float mu = s1 * (1.f / 256.f);
    const float rs = rsqrtf(s2 * (1.f / 256.f) - mu * mu + 1e-5f);
    const float4 g4 = *(const float4*)&g_pf[lane * 4];
    const float4 b4 = *(const float4*)&b_pf[lane * 4];
    float4 p;
    p.x = t4.x + (my4.x - mu) * rs * g4.x + b4.x;
    p.y = t4.y + (my4.y - mu) * rs * g4.y + b4.y;
    p.z = t4.z + (my4.z - mu) * rs * g4.z + b4.z;
    p.w = t4.w + (my4.w - mu) * rs * g4.w + b4.w;
    *(float4*)&PF[idx] = p;
  }
}

// ---------------- Kernel F: gate/up + silu -> HID ----------------
extern "C" __global__ void __launch_bounds__(256) k_gateup(
    const float* __restrict__ PF, const float* __restrict__ Wg,
    const float* __restrict__ Wu, float* __restrict__ HID) {
  __shared__ float4 x4s[16 * 64];   // [d4][b]
  __shared__ float ustage[64 * 64]; // [b][f_local]
  const int t = threadIdx.x;
  const int l = blockIdx.x, fg = blockIdx.y;
  const int which = t >> 7;
  const int bblk = (t >> 3) & 15, fblk = t & 7;
  const int b0 = bblk * 4, fl0 = fblk * 8;
  const float* W = which ? Wu : Wg;
  const float* wp = W + l * 262144 + fg * 64 + fl0;
  float acc[4][8];
#pragma unroll
  for (int i = 0; i < 4; ++i)
#pragma unroll
    for (int jf = 0; jf < 8; ++jf) acc[i][jf] = 0.f;
  for (int dc = 0; dc < 4; ++dc) {
    __syncthreads();
#pragma unroll
    for (int jj = 0; jj < 4; ++jj) {
      const int flat = jj * 1024 + t * 4;
      const int bb = flat >> 6, dl = flat & 63;
      x4s[(dl >> 2) * 64 + bb] =
          *(const float4*)&PF[bb * 16384 + l * 256 + dc * 64 + dl];
    }
    __syncthreads();
    for (int d4 = 0; d4 < 16; ++d4) {
      float xa[4][4];
#pragma unroll
      for (int i = 0; i < 4; ++i) {
        const float4 xv = x4s[d4 * 64 + b0 + i];
        xa[i][0] = xv.x; xa[i][1] = xv.y; xa[i][2] = xv.z; xa[i][3] = xv.w;
      }
      const int dbase = dc * 64 + d4 * 4;
#pragma unroll
      for (int m = 0; m < 4; ++m) {
        const float4 w0 = *(const float4*)&wp[(dbase + m) * 1024];
        const float4 w1 = *(const float4*)&wp[(dbase + m) * 1024 + 4];
        const float wj[8] = {w0.x, w0.y, w0.z, w0.w, w1.x, w1.y, w1.z, w1.w};
#pragma unroll
        for (int i = 0; i < 4; ++i)
#pragma unroll
          for (int jf = 0; jf < 8; ++jf) acc[i][jf] += xa[i][m] * wj[jf];
      }
    }
  }
  __syncthreads();
  if (which) {
#pragma unroll
    for (int i = 0; i < 4; ++i) {
      float4 a0, a1;
      a0.x = acc[i][0]; a0.y = acc[i][1]; a0.z = acc[i][2]; a0.w = acc[i][3];
      a1.x = acc[i][4]; a1.y = acc[i][5]; a1.z = acc[i][6]; a1.w = acc[i][7];
      *(float4*)&ustage[(b0 + i) * 64 + fl0] = a0;
      *(float4*)&ustage[(b0 + i) * 64 + fl0 + 4] = a1;
    }
  }
  __syncthreads();
  if (!which) {
#pragma unroll
    for (int i = 0; i < 4; ++i) {
      float h[8];
#pragma unroll
      for (int jf = 0; jf < 8; ++jf) {
        const float gval = acc[i][jf];
        const float uval = ustage[(b0 + i) * 64 + fl0 + jf];
        h[jf] = gval / (1.f + __expf(-gval)) * uval;  // silu(g)*u
      }
      float4 h0, h1;
      h0.x = h[0]; h0.y = h[1]; h0.z = h[2]; h0.w = h[3];
      h1.x = h[4]; h1.y = h[5]; h1.z = h[6]; h1.w = h[7];
      *(float4*)&HID[l * 65536 + (b0 + i) * 1024 + fg * 64 + fl0] = h0;
      *(float4*)&HID[l * 65536 + (b0 + i) * 1024 + fg * 64 + fl0 + 4] = h1;
    }
  }
}

// ---------------- Kernel G: down-proj partials ----------------
extern "C" __global__ void __launch_bounds__(256) k_down(
    const float* __restrict__ HID, const float* __restrict__ Wd,
    float* __restrict__ P0, float* __restrict__ P1) {
  __shared__ float4 h4s[16 * 64];  // [f4][b]
  const int t = threadIdx.x;
  const int l = blockIdx.x, dh = blockIdx.y, fh = blockIdx.z;
  const int bblk = t >> 4, dblk = t & 15;
  const int b0 = bblk * 4, dl0 = dblk * 8;
  const float* wp = Wd + l * 262144 + dh * 128 + dl0;
  float* pp = fh ? P1 : P0;
  float acc[4][8];
#pragma unroll
  for (int i = 0; i < 4; ++i)
#pragma unroll
    for (int jd = 0; jd < 8; ++jd) acc[i][jd] = 0.f;
  for (int fc = 0; fc < 8; ++fc) {
    const int fbase = fh * 512 + fc * 64;
    __syncthreads();
#pragma unroll
    for (int jj = 0; jj < 4; ++jj) {
      const int flat = jj * 1024 + t * 4;
      const int bb = flat >> 6, fl = flat & 63;
      h4s[(fl >> 2) * 64 + bb] =
          *(const float4*)&HID[l * 65536 + bb * 1024 + fbase + fl];
    }
    __syncthreads();
    for (int f4 = 0; f4 < 16; ++f4) {
      float xa[4][4];
#pragma unroll
      for (int i = 0; i < 4; ++i) {
        const float4 xv = h4s[f4 * 64 + b0 + i];
        xa[i][0] = xv.x; xa[i][1] = xv.y; xa[i][2] = xv.z; xa[i][3] = xv.w;
      }
#pragma unroll
      for (int m = 0; m < 4; ++m) {
        const int f = fbase + f4 * 4 + m;
        const float4 w0 = *(const float4*)&wp[f * 256];
        const float4 w1 = *(const float4*)&wp[f * 256 + 4];
        const float wj[8] = {w0.x, w0.y, w0.z, w0.w, w1.x, w1.y, w1.z, w1.w};
#pragma unroll
        for (int i = 0; i < 4; ++i)
#pragma unroll
          for (int jd = 0; jd < 8; ++jd) acc[i][jd] += xa[i][m] * wj[jd];
      }
    }
  }
#pragma unroll
  for (int i = 0; i < 4; ++i) {
    float4 a0, a1;
    a0.x = acc[i][0]; a0.y = acc[i][1]; a0.z = acc[i][2]; a0.w = acc[i][3];
    a1.x = acc[i][4]; a1.y = acc[i][5]; a1.z = acc[i][6]; a1.w = acc[i][7];
    *(float4*)&pp[(b0 + i) * 16384 + l * 256 + dh * 128 + dl0] = a0;
    *(float4*)&pp[(b0 + i) * 16384 + l * 256 + dh * 128 + dl0 + 4] = a1;
  }
}

// ---------------- Kernel H: final outputs ----------------
extern "C" __global__ void __launch_bounds__(256) k_final(
    const float* __restrict__ MX, const float* __restrict__ MY,
    const float* __restrict__ P0, const float* __restrict__ P1,
    const float* __restrict__ g_po, const float* __restrict__ b_po,
    float* __restrict__ out) {
  const int lane = threadIdx.x & 63;
  const int row = blockIdx.x * 4 + (threadIdx.x >> 6);
  const int idx = row * 256 + lane * 4;
  const float4 mx4 = *(const float4*)&MX[idx];
  const float4 my4 = *(const float4*)&MY[idx];
  const float4 p04 = *(const float4*)&P0[idx];
  const float4 p14 = *(const float4*)&P1[idx];
  float4 f4;
  f4.x = p04.x + p14.x; f4.y = p04.y + p14.y;
  f4.z = p04.z + p14.z; f4.w = p04.w + p14.w;
  float4 ty;
  ty.x = my4.x + f4.x; ty.y = my4.y + f4.y;
  ty.z = my4.z + f4.z; ty.w = my4.w + f4.w;
  *(float4*)&out[1048576 + idx] = ty;
  float4 tx;
  tx.x = mx4.x + f4.x; tx.y = mx4.y + f4.y;
  tx.z = mx4.z + f4.z; tx.w = mx4.w + f4.w;
  float s1 = tx.x + tx.y + tx.z + tx.w;
  float s2 = tx.x * tx.x + tx.y * tx.y + tx.z * tx.z + tx.w * tx.w;
  s1 = wave_sum(s1); s2 = wave_sum(s2);
  const float mu = s1 * (1.f / 256.f);
  const float rs = rsqrtf(s2 * (1.f / 256.f) - mu * mu + 1e-5f);
  const float4 g4 = *(const float4*)&g_po[lane * 4];
  const float4 b4 = *(const float4*)&b_po[lane * 4];
  float4 ox;
  ox.x = (tx.x - mu) * rs * g4.x + b4.x;
  ox.y = (tx.y - mu) * rs * g4.y + b4.y;
  ox.z = (tx.z - mu) * rs * g4.z + b4.z;
  ox.w = (tx.w - mu) * rs * g4.w + b4.w;
  *(float4*)&out[idx] = ox;
}

extern "C" void kernel_launch(void* const* d_in, const int* in_sizes, int n_in,
                              void* d_out, int out_size, void* d_ws,
                              size_t ws_size, hipStream_t stream) {
  const float* sx = (const float*)d_in[0];
  const float* sy = (const float*)d_in[1];
  const float* Alog = (const float*)d_in[2];
  const float* W1 = (const float*)d_in[3];
  const float* WV = (const float*)d_in[4];
  const float* n2g = (const float*)d_in[5];
  const float* n2b = (const float*)d_in[6];
  const float* Wg = (const float*)d_in[7];
  const float* Wu = (const float*)d_in[8];
  const float* Wd = (const float*)d_in[9];
  const float* g_pm = (const float*)d_in[10];
  const float* b_pm = (const float*)d_in[11];
  const float* g_px = (const float*)d_in[12];
  const float* b_px = (const float*)d_in[13];
  const float* g_pf = (const float*)d_in[14];
  const float* b_pf = (const float*)d_in[15];
  const float* g_po = (const float*)d_in[16];
  const float* b_po = (const float*)d_in[17];
  float* ws = (float*)d_ws;
  float* Wmat = ws + 0;
  float* Aws = ws + 2097152;
  float* M = ws + 2113536;
  float* XL = ws + 3162112;
  float* GX = ws + 4210688;
  float* MX = ws + 5259264;
  float* MY = ws + 6307840;
  float* PF = ws + 7356416;
  float* HID = ws + 0;       // overlays dead Wmat/Aws/M/XL
  float* P0 = ws + 4210688;  // overlays dead GX
  float* P1 = ws + 8404992;
  float* out = (float*)d_out;

  k_sink<<<129, 256, 68608, stream>>>(Alog, W1, WV, Wmat, Aws);
  k_premix<<<1024, 256, 0, stream>>>(sx, sy, g_pm, b_pm, M);
  k_local<<<128, 256, 98304, stream>>>(M, Wmat, XL);
  k_globalmix<<<64, 256, 134144, stream>>>(XL, Aws, n2g, n2b, GX);
  k_mid<<<1024, 256, 0, stream>>>(sx, sy, GX, g_px, b_px, g_pf, b_pf, MX, MY, PF);
  k_gateup<<<dim3(64, 16), 256, 0, stream>>>(PF, Wg, Wu, HID);
  k_down<<<dim3(64, 2, 2), 256, 0, stream>>>(HID, Wd, P0, P1);
  k_final<<<1024, 256, 0, stream>>>(MX, MY, P0, P1, g_po, b_po, out);
}

// Round 2
// 364.261 us; speedup vs baseline: 1.4442x; 1.4442x over previous
//
#include <hip/hip_runtime.h>

// Sizes: B=64, T=64, D=256, N=128, K=128, BASIS=8, F=1024
// ws layout (floats):
//  Wmat @ 0        (2097152)  dead after k_local
//  Aws  @ 2097152  (16384)    g-scaled A; dead after k_globalmix
//  M    @ 2113536  (1048576)  dead after k_local
//  XL   @ 3162112  (1048576)  dead after k_globalmix
//  GX   @ 4210688  (1048576)  dead after k_mid
//  MX   @ 5259264  (1048576)
//  MY   @ 6307840  (1048576)
//  PF   @ 7356416  (1048576)  dead after k_gateup
//  HID  @ 0        (bf16, 4194304 elems = 2097152 f32 slots) overlays Wmat
//  P0   @ 2113536  overlays M ; P1 @ 3162112 overlays XL
//  P2   @ 4210688  overlays GX; P3 @ 8404992
//  CG   @ 8404992 (128), CB @ 8405248 (128) — used sink->globalmix, then P3 overwrites
// total 9453568 floats = 37.8 MB (same as round 1)

using f32x4 = __attribute__((ext_vector_type(4))) float;
using s16x8 = __attribute__((ext_vector_type(8))) short;

__device__ __forceinline__ float wave_sum(float x) {
#pragma unroll
  for (int o = 32; o >= 1; o >>= 1) x += __shfl_xor(x, o, 64);
  return x;
}

__device__ __forceinline__ unsigned short f2bf(float x) {
  union { float f; unsigned u; } c; c.f = x;
  return (unsigned short)((c.u + 0x7fffu + ((c.u >> 16) & 1u)) >> 16);
}
__device__ __forceinline__ unsigned pack2(float a, float b) {
  return (unsigned)f2bf(a) | ((unsigned)f2bf(b) << 16);
}

// ---------------- Kernel A: sinkhorn via dual potentials ----------------
extern "C" __global__ void __launch_bounds__(256) k_sink(
    const float* __restrict__ Alog, const float* __restrict__ W1,
    const float* __restrict__ WV, float* __restrict__ Wout,
    float* __restrict__ Aout, const float* __restrict__ g2,
    const float* __restrict__ b2, float* __restrict__ CG,
    float* __restrict__ CB) {
  extern __shared__ float sm[];
  float* laT = sm;              // [128][132]
  float* u_s = sm + 128 * 132;
  float* v_s = u_s + 128;
  const int t = threadIdx.x;
  const int n = blockIdx.x;
  const int r = t >> 1, j = t & 1, c0 = j * 64;
  float la[64];
  if (n < 128) {
    float w1v[8];
#pragma unroll
    for (int s = 0; s < 8; ++s) w1v[s] = W1[n * 8 + s];
#pragma unroll
    for (int i4 = 0; i4 < 16; ++i4) {
      float a0 = 0.f, a1 = 0.f, a2 = 0.f, a3 = 0.f;
#pragma unroll
      for (int s = 0; s < 8; ++s) {
        const float4 wv = *(const float4*)&WV[s * 16384 + r * 128 + c0 + i4 * 4];
        a0 += w1v[s] * wv.x; a1 += w1v[s] * wv.y;
        a2 += w1v[s] * wv.z; a3 += w1v[s] * wv.w;
      }
      la[i4 * 4 + 0] = 5.f * a0; la[i4 * 4 + 1] = 5.f * a1;
      la[i4 * 4 + 2] = 5.f * a2; la[i4 * 4 + 3] = 5.f * a3;
    }
  } else {
#pragma unroll
    for (int i4 = 0; i4 < 16; ++i4) {
      const float4 av = *(const float4*)&Alog[r * 128 + c0 + i4 * 4];
      la[i4 * 4 + 0] = 5.f * av.x; la[i4 * 4 + 1] = 5.f * av.y;
      la[i4 * 4 + 2] = 5.f * av.z; la[i4 * 4 + 3] = 5.f * av.w;
    }
  }
#pragma unroll
  for (int i = 0; i < 64; ++i) laT[(c0 + i) * 132 + r] = la[i];
  if (t < 128) { u_s[t] = 0.f; v_s[t] = 0.f; }
  __syncthreads();
  for (int it = 0; it < 20; ++it) {
    float s = 0.f;
#pragma unroll
    for (int i4 = 0; i4 < 16; ++i4) {
      const float4 v4 = *(const float4*)&v_s[c0 + i4 * 4];
      s += __expf(la[i4 * 4 + 0] - v4.x) + __expf(la[i4 * 4 + 1] - v4.y) +
           __expf(la[i4 * 4 + 2] - v4.z) + __expf(la[i4 * 4 + 3] - v4.w);
    }
    s += __shfl_xor(s, 1, 64);
    if (j == 0) u_s[r] = __logf(s);
    __syncthreads();
    float sv = 0.f;
#pragma unroll
    for (int i4 = 0; i4 < 16; ++i4) {
      const float4 u4 = *(const float4*)&u_s[c0 + i4 * 4];
      const float4 l4 = *(const float4*)&laT[r * 132 + c0 + i4 * 4];
      sv += __expf(l4.x - u4.x) + __expf(l4.y - u4.y) +
            __expf(l4.z - u4.z) + __expf(l4.w - u4.w);
    }
    sv += __shfl_xor(sv, 1, 64);
    if (j == 0) v_s[r] = __logf(sv);
    __syncthreads();
  }
  const float ur = u_s[r];
  if (n < 128) {
    float* outp = Wout + n * 16384;
#pragma unroll
    for (int i4 = 0; i4 < 16; ++i4) {
      const float4 v4 = *(const float4*)&v_s[c0 + i4 * 4];
      float4 p;
      p.x = __expf(la[i4 * 4 + 0] - ur - v4.x);
      p.y = __expf(la[i4 * 4 + 1] - ur - v4.y);
      p.z = __expf(la[i4 * 4 + 2] - ur - v4.z);
      p.w = __expf(la[i4 * 4 + 3] - ur - v4.w);
      *(float4*)&outp[r * 128 + c0 + i4 * 4] = p;
    }
  } else {
    const float gr = g2[r], br = b2[r];
#pragma unroll
    for (int i4 = 0; i4 < 16; ++i4) {
      const float4 v4 = *(const float4*)&v_s[c0 + i4 * 4];
      float4 p;
      p.x = __expf(la[i4 * 4 + 0] - ur - v4.x);
      p.y = __expf(la[i4 * 4 + 1] - ur - v4.y);
      p.z = __expf(la[i4 * 4 + 2] - ur - v4.z);
      p.w = __expf(la[i4 * 4 + 3] - ur - v4.w);
      la[i4 * 4 + 0] = p.x; la[i4 * 4 + 1] = p.y;
      la[i4 * 4 + 2] = p.z; la[i4 * 4 + 3] = p.w;
      float4 ps; ps.x = gr * p.x; ps.y = gr * p.y; ps.z = gr * p.z; ps.w = gr * p.w;
      *(float4*)&Aout[r * 128 + c0 + i4 * 4] = ps;  // g-scaled A
    }
    __syncthreads();
#pragma unroll
    for (int i = 0; i < 64; ++i) laT[(c0 + i) * 132 + r] = gr * la[i];
    __syncthreads();
    if (t < 128) {
      float s = 0.f;
      for (int m = 0; m < 128; ++m) s += laT[t * 132 + m];
      CG[t] = s;
    }
    __syncthreads();
#pragma unroll
    for (int i = 0; i < 64; ++i) laT[(c0 + i) * 132 + r] = br * la[i];
    __syncthreads();
    if (t < 128) {
      float s = 0.f;
      for (int m = 0; m < 128; ++m) s += laT[t * 132 + m];
      CB[t] = s;
    }
  }
}

// ---------------- Kernel B: mixing_input = src_x + LN(src_y) ----------------
extern "C" __global__ void __launch_bounds__(256) k_premix(
    const float* __restrict__ sx, const float* __restrict__ sy,
    const float* __restrict__ g, const float* __restrict__ b,
    float* __restrict__ M) {
  const int lane = threadIdx.x & 63;
  const int row = blockIdx.x * 4 + (threadIdx.x >> 6);
  const int idx = row * 256 + lane * 4;
  const float4 y4 = *(const float4*)&sy[idx];
  const float4 x4 = *(const float4*)&sx[idx];
  float s1 = y4.x + y4.y + y4.z + y4.w;
  float s2 = y4.x * y4.x + y4.y * y4.y + y4.z * y4.z + y4.w * y4.w;
  s1 = wave_sum(s1); s2 = wave_sum(s2);
  const float mu = s1 * (1.f / 256.f);
  const float rs = rsqrtf(s2 * (1.f / 256.f) - mu * mu + 1e-5f);
  const float4 g4 = *(const float4*)&g[lane * 4];
  const float4 b4 = *(const float4*)&b[lane * 4];
  float4 m4;
  m4.x = x4.x + (y4.x - mu) * rs * g4.x + b4.x;
  m4.y = x4.y + (y4.y - mu) * rs * g4.y + b4.y;
  m4.z = x4.z + (y4.z - mu) * rs * g4.z + b4.z;
  m4.w = x4.w + (y4.w - mu) * rs * g4.w + b4.w;
  *(float4*)&M[idx] = m4;
}

// ---------------- Kernel C: XL[b,n,:] = xr[b,n,:] @ W[n] (batch-split) ------
extern "C" __global__ void __launch_bounds__(256) k_local(
    const float* __restrict__ M, const float* __restrict__ Wmat,
    float* __restrict__ XL) {
  extern __shared__ float sm[];
  float* Wl = sm;                       // [128][128]
  float4* xr4 = (float4*)(sm + 16384);  // [32 k4][32 b]
  const int t = threadIdx.x;
  const int n = blockIdx.x;
  const int bh = blockIdx.y;
  const int hi = n & 1, t2 = n >> 1;
#pragma unroll
  for (int jj = 0; jj < 16; ++jj)
    *(float4*)&Wl[jj * 1024 + t * 4] =
        *(const float4*)&Wmat[n * 16384 + jj * 1024 + t * 4];
  {
    const int bl = t & 31, qg = t >> 5;
#pragma unroll
    for (int i = 0; i < 4; ++i) {
      const int q = qg * 4 + i;
      xr4[q * 32 + bl] =
          *(const float4*)&M[(bh * 32 + bl) * 16384 + (hi * 32 + q) * 256 + t2 * 4];
    }
  }
  __syncthreads();
  const int kblk = t & 31, bblk = t >> 5;
  const int ko0 = kblk * 4, b0 = bblk * 4;
  float acc[4][4];
#pragma unroll
  for (int i = 0; i < 4; ++i)
    acc[i][0] = acc[i][1] = acc[i][2] = acc[i][3] = 0.f;
  for (int q = 0; q < 32; ++q) {
    const float4 w0 = *(const float4*)&Wl[(4 * q + 0) * 128 + ko0];
    const float4 w1 = *(const float4*)&Wl[(4 * q + 1) * 128 + ko0];
    const float4 w2 = *(const float4*)&Wl[(4 * q + 2) * 128 + ko0];
    const float4 w3 = *(const float4*)&Wl[(4 * q + 3) * 128 + ko0];
#pragma unroll
    for (int i = 0; i < 4; ++i) {
      const float4 xv = xr4[q * 32 + b0 + i];
      acc[i][0] += xv.x * w0.x + xv.y * w1.x + xv.z * w2.x + xv.w * w3.x;
      acc[i][1] += xv.x * w0.y + xv.y * w1.y + xv.z * w2.y + xv.w * w3.y;
      acc[i][2] += xv.x * w0.z + xv.y * w1.z + xv.z * w2.z + xv.w * w3.z;
      acc[i][3] += xv.x * w0.w + xv.y * w1.w + xv.z * w2.w + xv.w * w3.w;
    }
  }
#pragma unroll
  for (int i = 0; i < 4; ++i) {
    float4 o;
    o.x = acc[i][0]; o.y = acc[i][1]; o.z = acc[i][2]; o.w = acc[i][3];
    *(float4*)&XL[(bh * 32 + b0 + i) * 16384 + n * 128 + ko0] = o;
  }
}

// --------- Kernel D: folded column-LN + @A (split b,kq,nh) -> GX ---------
extern "C" __global__ void __launch_bounds__(256) k_globalmix(
    const float* __restrict__ XLg, const float* __restrict__ Ag_glob,
    const float* __restrict__ CG, const float* __restrict__ CB,
    float* __restrict__ GX) {
  __shared__ float Agl[128 * 64];  // [m][n-half]
  __shared__ float XLl[128 * 36];  // [m][32k +pad]
  __shared__ float ps1[256], ps2[256], mus[32], rss[32];
  const int t = threadIdx.x;
  const int b = blockIdx.x, kq = blockIdx.y, nh = blockIdx.z;
#pragma unroll
  for (int p = 0; p < 4; ++p) {
    const int m = p * 32 + (t >> 3), k4 = t & 7;
    *(float4*)&XLl[m * 36 + k4 * 4] =
        *(const float4*)&XLg[b * 16384 + m * 128 + kq * 32 + k4 * 4];
  }
#pragma unroll
  for (int p = 0; p < 8; ++p) {
    const int m = p * 16 + (t >> 4), c4 = t & 15;
    *(float4*)&Agl[m * 64 + c4 * 4] =
        *(const float4*)&Ag_glob[m * 128 + nh * 64 + c4 * 4];
  }
  __syncthreads();
  {
    const int k = t & 31, ms = t >> 5;
    float s1 = 0.f, s2 = 0.f;
    for (int m = ms * 16; m < ms * 16 + 16; ++m) {
      const float x = XLl[m * 36 + k];
      s1 += x; s2 += x * x;
    }
    ps1[ms * 32 + k] = s1; ps2[ms * 32 + k] = s2;
  }
  __syncthreads();
  if (t < 32) {
    float s1 = 0.f, s2 = 0.f;
    for (int i = 0; i < 8; ++i) { s1 += ps1[i * 32 + t]; s2 += ps2[i * 32 + t]; }
    const float mu = s1 * (1.f / 128.f);
    mus[t] = mu;
    rss[t] = rsqrtf(s2 * (1.f / 128.f) - mu * mu + 1e-5f);
  }
  __syncthreads();
  const int ln = 2 * (t >> 3), k0 = 4 * (t & 7);
  float acc[2][4];
  acc[0][0] = acc[0][1] = acc[0][2] = acc[0][3] = 0.f;
  acc[1][0] = acc[1][1] = acc[1][2] = acc[1][3] = 0.f;
  for (int m = 0; m < 128; ++m) {
    const float2 a2 = *(const float2*)&Agl[m * 64 + ln];
    const float4 x4 = *(const float4*)&XLl[m * 36 + k0];
    acc[0][0] += a2.x * x4.x; acc[0][1] += a2.x * x4.y;
    acc[0][2] += a2.x * x4.z; acc[0][3] += a2.x * x4.w;
    acc[1][0] += a2.y * x4.x; acc[1][1] += a2.y * x4.y;
    acc[1][2] += a2.y * x4.z; acc[1][3] += a2.y * x4.w;
  }
#pragma unroll
  for (int jj = 0; jj < 2; ++jj) {
    const int ng = nh * 64 + ln + jj;
    const float cgn = CG[ng], cbn = CB[ng];
    float4 o;
    o.x = rss[k0 + 0] * (acc[jj][0] - mus[k0 + 0] * cgn) + cbn;
    o.y = rss[k0 + 1] * (acc[jj][1] - mus[k0 + 1] * cgn) + cbn;
    o.z = rss[k0 + 2] * (acc[jj][2] - mus[k0 + 2] * cgn) + cbn;
    o.w = rss[k0 + 3] * (acc[jj][3] - mus[k0 + 3] * cgn) + cbn;
    *(float4*)&GX[b * 16384 + ng * 128 + kq * 32 + k0] = o;
  }
}

// ---------------- Kernel E: mid_x / mid_y / pffn ----------------
extern "C" __global__ void __launch_bounds__(256) k_mid(
    const float* __restrict__ sx, const float* __restrict__ sy,
    const float* __restrict__ GX, const float* __restrict__ g_px,
    const float* __restrict__ b_px, const float* __restrict__ g_pf,
    const float* __restrict__ b_pf, float* __restrict__ MX,
    float* __restrict__ MY, float* __restrict__ PF) {
  const int lane = threadIdx.x & 63;
  const int row = blockIdx.x * 4 + (threadIdx.x >> 6);
  const int idx = row * 256 + lane * 4;
  const float4 x4 = *(const float4*)&sx[idx];
  const float4 y4 = *(const float4*)&sy[idx];
  const float4 h4 = *(const float4*)&GX[idx];
  float4 t4;
  t4.x = x4.x + h4.x; t4.y = x4.y + h4.y; t4.z = x4.z + h4.z; t4.w = x4.w + h4.w;
  {
    float s1 = t4.x + t4.y + t4.z + t4.w;
    float s2 = t4.x * t4.x + t4.y * t4.y + t4.z * t4.z + t4.w * t4.w;
    s1 = wave_sum(s1); s2 = wave_sum(s2);
    const float mu = s1 * (1.f / 256.f);
    const float rs = rsqrtf(s2 * (1.f / 256.f) - mu * mu + 1e-5f);
    const float4 g4 = *(const float4*)&g_px[lane * 4];
    const float4 b4 = *(const float4*)&b_px[lane * 4];
    t4.x = (t4.x - mu) * rs * g4.x + b4.x;
    t4.y = (t4.y - mu) * rs * g4.y + b4.y;
    t4.z = (t4.z - mu) * rs * g4.z + b4.z;
    t4.w = (t4.w - mu) * rs * g4.w + b4.w;
  }
  *(float4*)&MX[idx] = t4;
  float4 my4;
  my4.x = y4.x + h4.x; my4.y = y4.y + h4.y;
  my4.z = y4.z + h4.z; my4.w = y4.w + h4.w;
  *(float4*)&MY[idx] = my4;
  {
    float s1 = my4.x + my4.y + my4.z + my4.w;
    float s2 = my4.x * my4.x + my4.y * my4.y + my4.z * my4.z + my4.w * my4.w;
    s1 = wave_sum(s1); s2 = wave_sum(s2);
    const float mu = s1 * (1.f / 256.f);
    const float rs = rsqrtf(s2 * (1.f / 256.f) - mu * mu + 1e-5f);
    const float4 g4 = *(const float4*)&g_pf[lane * 4];
    const float4 b4 = *(const float4*)&b_pf[lane * 4];
    float4 p;
    p.x = t4.x + (my4.x - mu) * rs * g4.x + b4.x;
    p.y = t4.y + (my4.y - mu) * rs * g4.y + b4.y;
    p.z = t4.z + (my4.z - mu) * rs * g4.z + b4.z;
    p.w = t4.w + (my4.w - mu) * rs * g4.w + b4.w;
    *(float4*)&PF[idx] = p;
  }
}

// ---------------- Kernel F: gate/up MFMA + silu -> HID (bf16) ----------------
// Block: (l, fg); computes 64b x 64f of gate AND up, K=256. 4 waves, wave=m-tile.
extern "C" __global__ void __launch_bounds__(256) k_gateup(
    const float* __restrict__ PF, const float* __restrict__ Wg,
    const float* __restrict__ Wu, unsigned short* __restrict__ HID) {
  __shared__ __align__(16) char XsB[64 * 512];    // [b][256k] bf16, swz
  __shared__ __align__(16) char WsB[128 * 144];   // [n][64k+pad] bf16
  const int t = threadIdx.x;
  const int l = blockIdx.x, fg = blockIdx.y;
  const int lane = t & 63, wid = t >> 6;
  // stage X = PF[:, l, :] as bf16, swizzled
  {
    const int b = t >> 2, seg = t & 3;
    const float* src = PF + b * 16384 + l * 256 + seg * 64;
#pragma unroll
    for (int j = 0; j < 8; ++j) {
      const int d0 = seg * 64 + j * 8;
      const float4 v0 = *(const float4*)&src[j * 8];
      const float4 v1 = *(const float4*)&src[j * 8 + 4];
      uint4 w;
      w.x = pack2(v0.x, v0.y); w.y = pack2(v0.z, v0.w);
      w.z = pack2(v1.x, v1.y); w.w = pack2(v1.z, v1.w);
      *(uint4*)(XsB + b * 512 + ((d0 * 2) ^ ((b & 7) << 4))) = w;
    }
  }
  f32x4 acc[8];
#pragma unroll
  for (int i = 0; i < 8; ++i) acc[i] = (f32x4){0.f, 0.f, 0.f, 0.f};
  const int n_st = t & 127, khalf = t >> 7;
  for (int c = 0; c < 4; ++c) {
    if (c) __syncthreads();
    // stage W chunk: k = c*64 .. +64, transposed [n][k] bf16
    {
      const float* Wsrc = (n_st < 64)
          ? (Wg + (size_t)l * 262144 + fg * 64 + n_st)
          : (Wu + (size_t)l * 262144 + fg * 64 + (n_st - 64));
#pragma unroll
      for (int p = 0; p < 4; ++p) {
        const int k0 = c * 64 + khalf * 8 + p * 16;
        float v[8];
#pragma unroll
        for (int i = 0; i < 8; ++i) v[i] = Wsrc[(size_t)(k0 + i) * 1024];
        uint4 w;
        w.x = pack2(v[0], v[1]); w.y = pack2(v[2], v[3]);
        w.z = pack2(v[4], v[5]); w.w = pack2(v[6], v[7]);
        *(uint4*)(WsB + n_st * 144 + (k0 & 63) * 2) = w;
      }
    }
    __syncthreads();
#pragma unroll
    for (int kt = 0; kt < 2; ++kt) {
      const int brow = wid * 16 + (lane & 15);
      const int koff = c * 64 + kt * 32 + (lane >> 4) * 8;
      const s16x8 af = *(const s16x8*)(XsB + brow * 512 + ((koff * 2) ^ ((brow & 7) << 4)));
#pragma unroll
      for (int nt = 0; nt < 8; ++nt) {
        const s16x8 bfr = *(const s16x8*)(WsB + (nt * 16 + (lane & 15)) * 144 +
                                          kt * 64 + (lane >> 4) * 16);
        acc[nt] = __builtin_amdgcn_mfma_f32_16x16x32_bf16(af, bfr, acc[nt], 0, 0, 0);
      }
    }
  }
  // epilogue: silu(gate)*up, store bf16
#pragma unroll
  for (int nt = 0; nt < 4; ++nt) {
#pragma unroll
    for (int r = 0; r < 4; ++r) {
      const float g = acc[nt][r];
      const float u = acc[nt + 4][r];
      const float h = g / (1.f + __expf(-g)) * u;
      const int b = wid * 16 + (lane >> 4) * 4 + r;
      const int f = fg * 64 + nt * 16 + (lane & 15);
      HID[(size_t)l * 65536 + b * 1024 + f] = f2bf(h);
    }
  }
}

// ---------------- Kernel G: down-proj MFMA partials ----------------
// Block: (l, dh, kq): M=64b, N=128d, K=256f quarter -> P[kq]
extern "C" __global__ void __launch_bounds__(256) k_down(
    const unsigned short* __restrict__ HID, const float* __restrict__ Wd,
    float* __restrict__ P0, float* __restrict__ P1, float* __restrict__ P2,
    float* __restrict__ P3) {
  __shared__ __align__(16) char HsB[64 * 512];   // [b][256k] bf16, swz
  __shared__ __align__(16) char WsB[128 * 144];  // [d][64k+pad] bf16
  const int t = threadIdx.x;
  const int l = blockIdx.x, dh = blockIdx.y, kq = blockIdx.z;
  const int lane = t & 63, wid = t >> 6;
  {
    const int b = t >> 2, seg = t & 3;
    const unsigned short* src = HID + (size_t)l * 65536 + b * 1024 + kq * 256 + seg * 64;
#pragma unroll
    for (int j = 0; j < 8; ++j) {
      const int k0 = seg * 64 + j * 8;
      const uint4 w = *(const uint4*)&src[j * 8];
      *(uint4*)(HsB + b * 512 + ((k0 * 2) ^ ((b & 7) << 4))) = w;
    }
  }
  f32x4 acc[8];
#pragma unroll
  for (int i = 0; i < 8; ++i) acc[i] = (f32x4){0.f, 0.f, 0.f, 0.f};
  const int n_st = t & 127, khalf = t >> 7;
  for (int c = 0; c < 4; ++c) {
    if (c) __syncthreads();
    {
      const float* Wsrc = Wd + (size_t)l * 262144 + dh * 128 + n_st;
#pragma unroll
      for (int p = 0; p < 4; ++p) {
        const int k0 = c * 64 + khalf * 8 + p * 16;
        const int kg = kq * 256 + k0;
        float v[8];
#pragma unroll
        for (int i = 0; i < 8; ++i) v[i] = Wsrc[(size_t)(kg + i) * 256];
        uint4 w;
        w.x = pack2(v[0], v[1]); w.y = pack2(v[2], v[3]);
        w.z = pack2(v[4], v[5]); w.w = pack2(v[6], v[7]);
        *(uint4*)(WsB + n_st * 144 + (k0 & 63) * 2) = w;
      }
    }
    __syncthreads();
#pragma unroll
    for (int kt = 0; kt < 2; ++kt) {
      const int brow = wid * 16 + (lane & 15);
      const int koff = c * 64 + kt * 32 + (lane >> 4) * 8;
      const s16x8 af = *(const s16x8*)(HsB + brow * 512 + ((koff * 2) ^ ((brow & 7) << 4)));
#pragma unroll
      for (int nt = 0; nt < 8; ++nt) {
        const s16x8 bfr = *(const s16x8*)(WsB + (nt * 16 + (lane & 15)) * 144 +
                                          kt * 64 + (lane >> 4) * 16);
        acc[nt] = __builtin_amdgcn_mfma_f32_16x16x32_bf16(af, bfr, acc[nt], 0, 0, 0);
      }
    }
  }
  float* P = (kq == 0) ? P0 : (kq == 1) ? P1 : (kq == 2) ? P2 : P3;
#pragma unroll
  for (int nt = 0; nt < 8; ++nt) {
#pragma unroll
    for (int r = 0; r < 4; ++r) {
      const int b = wid * 16 + (lane >> 4) * 4 + r;
      const int d = dh * 128 + nt * 16 + (lane & 15);
      P[(size_t)b * 16384 + l * 256 + d] = acc[nt][r];
    }
  }
}

// ---------------- Kernel H: final outputs ----------------
extern "C" __global__ void __launch_bounds__(256) k_final(
    const float* __restrict__ MX, const float* __restrict__ MY,
    const float* __restrict__ P0, const float* __restrict__ P1,
    const float* __restrict__ P2, const float* __restrict__ P3,
    const float* __restrict__ g_po, const float* __restrict__ b_po,
    float* __restrict__ out) {
  const int lane = threadIdx.x & 63;
  const int row = blockIdx.x * 4 + (threadIdx.x >> 6);
  const int idx = row * 256 + lane * 4;
  const float4 mx4 = *(const float4*)&MX[idx];
  const float4 my4 = *(const float4*)&MY[idx];
  const float4 p04 = *(const float4*)&P0[idx];
  const float4 p14 = *(const float4*)&P1[idx];
  const float4 p24 = *(const float4*)&P2[idx];
  const float4 p34 = *(const float4*)&P3[idx];
  float4 f4;
  f4.x = p04.x + p14.x + p24.x + p34.x;
  f4.y = p04.y + p14.y + p24.y + p34.y;
  f4.z = p04.z + p14.z + p24.z + p34.z;
  f4.w = p04.w + p14.w + p24.w + p34.w;
  float4 ty;
  ty.x = my4.x + f4.x; ty.y = my4.y + f4.y;
  ty.z = my4.z + f4.z; ty.w = my4.w + f4.w;
  *(float4*)&out[1048576 + idx] = ty;
  float4 tx;
  tx.x = mx4.x + f4.x; tx.y = mx4.y + f4.y;
  tx.z = mx4.z + f4.z; tx.w = mx4.w + f4.w;
  float s1 = tx.x + tx.y + tx.z + tx.w;
  float s2 = tx.x * tx.x + tx.y * tx.y + tx.z * tx.z + tx.w * tx.w;
  s1 = wave_sum(s1); s2 = wave_sum(s2);
  const float mu = s1 * (1.f / 256.f);
  const float rs = rsqrtf(s2 * (1.f / 256.f) - mu * mu + 1e-5f);
  const float4 g4 = *(const float4*)&g_po[lane * 4];
  const float4 b4 = *(const float4*)&b_po[lane * 4];
  float4 ox;
  ox.x = (tx.x - mu) * rs * g4.x + b4.x;
  ox.y = (tx.y - mu) * rs * g4.y + b4.y;
  ox.z = (tx.z - mu) * rs * g4.z + b4.z;
  ox.w = (tx.w - mu) * rs * g4.w + b4.w;
  *(float4*)&out[idx] = ox;
}

extern "C" void kernel_launch(void* const* d_in, const int* in_sizes, int n_in,
                              void* d_out, int out_size, void* d_ws,
                              size_t ws_size, hipStream_t stream) {
  const float* sx = (const float*)d_in[0];
  const float* sy = (const float*)d_in[1];
  const float* Alog = (const float*)d_in[2];
  const float* W1 = (const float*)d_in[3];
  const float* WV = (const float*)d_in[4];
  const float* n2g = (const float*)d_in[5];
  const float* n2b = (const float*)d_in[6];
  const float* Wg = (const float*)d_in[7];
  const float* Wu = (const float*)d_in[8];
  const float* Wd = (const float*)d_in[9];
  const float* g_pm = (const float*)d_in[10];
  const float* b_pm = (const float*)d_in[11];
  const float* g_px = (const float*)d_in[12];
  const float* b_px = (const float*)d_in[13];
  const float* g_pf = (const float*)d_in[14];
  const float* b_pf = (const float*)d_in[15];
  const float* g_po = (const float*)d_in[16];
  const float* b_po = (const float*)d_in[17];
  float* ws = (float*)d_ws;
  float* Wmat = ws + 0;
  float* Aws = ws + 2097152;
  float* M = ws + 2113536;
  float* XL = ws + 3162112;
  float* GX = ws + 4210688;
  float* MX = ws + 5259264;
  float* MY = ws + 6307840;
  float* PF = ws + 7356416;
  unsigned short* HID = (unsigned short*)(ws + 0);  // bf16, overlays dead Wmat
  float* P0 = ws + 2113536;  // overlays M
  float* P1 = ws + 3162112;  // overlays XL
  float* P2 = ws + 4210688;  // overlays GX
  float* P3 = ws + 8404992;
  float* CG = ws + 8404992;  // alive sink->globalmix, then P3 overwrites
  float* CB = ws + 8405248;
  float* out = (float*)d_out;

  k_sink<<<129, 256, 68608, stream>>>(Alog, W1, WV, Wmat, Aws, n2g, n2b, CG, CB);
  k_premix<<<1024, 256, 0, stream>>>(sx, sy, g_pm, b_pm, M);
  k_local<<<dim3(128, 2), 256, 81920, stream>>>(M, Wmat, XL);
  k_globalmix<<<dim3(64, 4, 2), 256, 0, stream>>>(XL, Aws, CG, CB, GX);
  k_mid<<<1024, 256, 0, stream>>>(sx, sy, GX, g_px, b_px, g_pf, b_pf, MX, MY, PF);
  k_gateup<<<dim3(64, 16), 256, 0, stream>>>(PF, Wg, Wu, HID);
  k_down<<<dim3(64, 2, 4), 256, 0, stream>>>(HID, Wd, P0, P1, P2, P3);
  k_final<<<1024, 256, 0, stream>>>(MX, MY, P0, P1, P2, P3, g_po, b_po, out);
}